// Round 9
// baseline (581.017 us; speedup 1.0000x reference)
//
#include <hip/hip_runtime.h>
#include <math.h>

#define THREADS 256   // 4 waves/block, 32 pts/wave, 128 pts/block

typedef __attribute__((ext_vector_type(8))) short bf16x8;
typedef __attribute__((ext_vector_type(4))) float f32x4;

// ---------------------------------------------------------------------------
// ws layout: [frag-major weight stream: 26 chunks x 16KB = 425984 B][volcl f32]
// Frag = 1KB (16 neurons x 32 k, 512 bf16). 416 frags total, 16 per chunk.
//   chunk 0       : L0 (W0 256x32): frags nt=0..15
//   chunks 1..24  : 3 hidden layers x 8 sub-chunks, order per layer:
//       A0 B0 A1 B1 A2 B2 A3 B3   (A: nt 0..7, B: nt 8..15; kq = ks pair)
//     within sub-chunk: idx = ksl*8 + ntl  (ksl 0..1, ntl 0..7)
//   chunk 25      : Wf frags ks=0..7 (rows>=4 zero) + 8 zero frags
#define NCHUNK 26
#define STREAM_BYTES (NCHUNK * 16384)

__device__ __host__ __forceinline__ int sigma_k(int k) {
    // bits [b7 b6 b5 | b4 b3 | b2 b1 | b0] -> [b7 b6 b5 | b2 | b4 b3 | b1 | b0]
    return (k & 0xE1) | ((k & 0x04) << 2) | ((k & 0x18) >> 1) | (k & 0x02);
}

__device__ __forceinline__ ushort f2bf(float f) {
    union { float f; unsigned u; } v; v.f = f;
    unsigned r = v.u + 0x7FFFu + ((v.u >> 16) & 1u);
    return (ushort)(r >> 16);
}

__device__ __forceinline__ float fast_sigmoid(float x) {
    return 1.0f / (1.0f + __expf(-x));
}

__device__ __forceinline__ unsigned cvt_pk_bf16(float lo, float hi) {
    unsigned d;
    asm("v_cvt_pk_bf16_f32 %0, %1, %2" : "=v"(d) : "v"(lo), "v"(hi));
    return d;
}

// ---------------- prep kernels ----------------
__global__ void build_frags(const float* __restrict__ W0,
                            const float* __restrict__ W1,
                            const float* __restrict__ W2,
                            const float* __restrict__ W3,
                            const float* __restrict__ Wf,
                            ushort* __restrict__ stream) {
    const int gid = blockIdx.x * 256 + threadIdx.x;   // 0 .. 26623
    const int f = gid >> 6;                            // frag 0..415
    if (f >= 416) return;
    const int lane = gid & 63;
    const int p16 = lane & 15, g = lane >> 4;
    ushort* dst = stream + (size_t)f * 512 + lane * 8;

    if (f < 16) {                       // L0: W0[f*16+p16][8g+i]
        const float* row = W0 + (size_t)(f * 16 + p16) * 32;
#pragma unroll
        for (int i = 0; i < 8; ++i) dst[i] = f2bf(row[8 * g + i]);
    } else if (f < 400) {
        const int t = f - 16;
        const int h = t >> 7;           // layer: 0,1,2 -> W1,W2,W3
        const int r = t & 127;
        const int sub = r >> 4;         // 0..7 = A0 B0 A1 B1 A2 B2 A3 B3
        const int idx = r & 15;
        const int q = sub & 1;          // 0=A(nt0..7) 1=B(nt8..15)
        const int kq = sub >> 1;        // ks pair 0..3
        const int ksl = idx >> 3;       // 0..1
        const int ntl = idx & 7;
        const int nt = q * 8 + ntl;
        const int ks = kq * 2 + ksl;
        const float* W = (h == 0) ? W1 : (h == 1) ? W2 : W3;
        const float* row = W + (size_t)(nt * 16 + p16) * 256;
#pragma unroll
        for (int i = 0; i < 8; ++i) dst[i] = f2bf(row[sigma_k(32 * ks + 8 * g + i)]);
    } else if (f < 408) {               // Wf
        const int ks = f - 400;
        if (p16 < 4) {
            const float* row = Wf + (size_t)p16 * 256;
#pragma unroll
            for (int i = 0; i < 8; ++i) dst[i] = f2bf(row[sigma_k(32 * ks + 8 * g + i)]);
        } else {
#pragma unroll
            for (int i = 0; i < 8; ++i) dst[i] = 0;
        }
    } else {
#pragma unroll
        for (int i = 0; i < 8; ++i) dst[i] = 0;
    }
}

// vol [B][32][32768] f32 -> dst [B*32768][32] f32 (channel-last)
__global__ void vol_chlast(const float* __restrict__ vol, float* __restrict__ dst, int nvox) {
    int v = blockIdx.x * 256 + threadIdx.x;
    if (v >= nvox) return;
    const int b = v >> 15, idx = v & 32767;
    const float* s = vol + (size_t)b * 32 * 32768 + idx;
    float* d = dst + (size_t)v * 32;
#pragma unroll
    for (int c = 0; c < 32; ++c) d[c] = s[(size_t)c * 32768];
}

// ---------------- main fused kernel ----------------
#define MF(a, b, c) __builtin_amdgcn_mfma_f32_16x16x32_bf16((a), (b), (c), 0, 0, 0)

__global__ __launch_bounds__(THREADS, 4)
void siren_pl(const float* __restrict__ points,
              const float* __restrict__ vol,
              const float* __restrict__ b0, const float* __restrict__ b1,
              const float* __restrict__ b2, const float* __restrict__ b3,
              const float* __restrict__ bfin,
              const ushort* __restrict__ Wstream,
              const float* __restrict__ volcl, int use_cl,
              float* __restrict__ out, long long total, int N) {
    __shared__ ushort ring[2][8192];    // 2 x 16KB -> 32KB/block -> 4 blocks/CU

    const int tid = (int)threadIdx.x;
    const int w = tid >> 6;             // wave 0..3
    const int lane = tid & 63;
    const int p16 = lane & 15;
    const int g = lane >> 4;

    const long long base = (long long)blockIdx.x * 128;

    auto stage = [&](int c) {
        if (c >= NCHUNK) return;
        const ushort* src = Wstream + (size_t)c * 8192;
        ushort* dstbase = &ring[c & 1][0];
#pragma unroll
        for (int q = 0; q < 4; ++q) {
            const int off = (q * 4 + w) * 512;   // elements; wave-uniform
            __builtin_amdgcn_global_load_lds(
                (const __attribute__((address_space(1))) unsigned int*)(src + off + lane * 8),
                (__attribute__((address_space(3))) unsigned int*)(dstbase + off),
                16, 0, 0);
        }
    };
    stage(0);
    stage(1);

    // ---- sample 2 points per lane: channels 8g..8g+7 ----
    bf16x8 af0[2];
    {
#pragma unroll
        for (int ptt = 0; ptt < 2; ++ptt) {
            const long long gidx = base + w * 32 + ptt * 16 + p16;
            const long long gp = gidx < total ? gidx : total - 1;
            const int bi = (int)(gp / N);
            const float* pp = points + gp * 3;
            const float sc = 1.0f / 0.6f;
            const float ix = (pp[0] * sc + 1.0f) * 16.0f - 0.5f;
            const float iy = (pp[1] * sc + 1.0f) * 16.0f - 0.5f;
            const float iz = (pp[2] * sc + 1.0f) * 16.0f - 0.5f;
            const float fx = floorf(ix), fy = floorf(iy), fz = floorf(iz);
            const float wx = ix - fx, wy = iy - fy, wz = iz - fz;
            const int x0 = (int)fminf(fmaxf(fx, 0.0f), 31.0f);
            const int x1 = (int)fminf(fmaxf(fx + 1.0f, 0.0f), 31.0f);
            const int y0 = (int)fminf(fmaxf(fy, 0.0f), 31.0f);
            const int y1 = (int)fminf(fmaxf(fy + 1.0f, 0.0f), 31.0f);
            const int z0 = (int)fminf(fmaxf(fz, 0.0f), 31.0f);
            const int z1 = (int)fminf(fmaxf(fz + 1.0f, 0.0f), 31.0f);
            const int i000 = (z0 * 32 + y0) * 32 + x0, i001 = (z0 * 32 + y0) * 32 + x1;
            const int i010 = (z0 * 32 + y1) * 32 + x0, i011 = (z0 * 32 + y1) * 32 + x1;
            const int i100 = (z1 * 32 + y0) * 32 + x0, i101 = (z1 * 32 + y0) * 32 + x1;
            const int i110 = (z1 * 32 + y1) * 32 + x0, i111 = (z1 * 32 + y1) * 32 + x1;
            const float omx = 1.0f - wx, omy = 1.0f - wy, omz = 1.0f - wz;
            const float w000 = omz * omy * omx, w001 = omz * omy * wx;
            const float w010 = omz * wy * omx,  w011 = omz * wy * wx;
            const float w100 = wz * omy * omx,  w101 = wz * omy * wx;
            const float w110 = wz * wy * omx,   w111 = wz * wy * wx;

            f32x4 a[2];
            if (use_cl) {
                const float* vb = volcl + (size_t)bi * 32768 * 32 + g * 8;
#pragma unroll
                for (int h = 0; h < 2; ++h) {
                    const float* vh = vb + h * 4;
                    a[h]  = w000 * *(const f32x4*)(vh + (size_t)i000 * 32);
                    a[h] += w001 * *(const f32x4*)(vh + (size_t)i001 * 32);
                    a[h] += w010 * *(const f32x4*)(vh + (size_t)i010 * 32);
                    a[h] += w011 * *(const f32x4*)(vh + (size_t)i011 * 32);
                    a[h] += w100 * *(const f32x4*)(vh + (size_t)i100 * 32);
                    a[h] += w101 * *(const f32x4*)(vh + (size_t)i101 * 32);
                    a[h] += w110 * *(const f32x4*)(vh + (size_t)i110 * 32);
                    a[h] += w111 * *(const f32x4*)(vh + (size_t)i111 * 32);
                }
            } else {
                const float* vb = vol + ((size_t)bi * 32 + (size_t)g * 8) * 32768;
#pragma unroll
                for (int c = 0; c < 8; ++c) {
                    const float* vc = vb + (size_t)c * 32768;
                    a[c >> 2][c & 3] =
                        vc[i000] * w000 + vc[i001] * w001 + vc[i010] * w010 + vc[i011] * w011 +
                        vc[i100] * w100 + vc[i101] * w101 + vc[i110] * w110 + vc[i111] * w111;
                }
            }
            union { bf16x8 v; unsigned u[4]; } pk;
            pk.u[0] = cvt_pk_bf16(a[0][0], a[0][1]);
            pk.u[1] = cvt_pk_bf16(a[0][2], a[0][3]);
            pk.u[2] = cvt_pk_bf16(a[1][0], a[1][1]);
            pk.u[3] = cvt_pk_bf16(a[1][2], a[1][3]);
            af0[ptt] = pk.v;
        }
    }

    f32x4 accA[2][8];   // nt 0..7
    f32x4 accB[2][8];   // nt 8..15
    bf16x8 bfr[2][8];   // activations, frag ks=0..7

    auto frag_at = [&](int slot, int idx) -> bf16x8 {
        return *(const bf16x8*)&ring[slot][idx * 512 + lane * 8];
    };
    auto init_half = [&](f32x4 (&A)[2][8], const float* __restrict__ b, int ntbase) {
#pragma unroll
        for (int m = 0; m < 8; ++m) {
            const f32x4 bv = *(const f32x4*)&b[(ntbase + m) * 16 + 4 * g];
            A[0][m] = bv; A[1][m] = bv;
        }
    };
    // pack 8 acc tiles (one nt-half) into bfr[ksbase..ksbase+3]
    auto pack_half = [&](f32x4 (&A)[2][8], int ksbase) {
#pragma unroll
        for (int ptt = 0; ptt < 2; ++ptt)
#pragma unroll
            for (int ks2 = 0; ks2 < 4; ++ks2) {
                union { bf16x8 v; unsigned u[4]; } pk;
#pragma unroll
                for (int j = 0; j < 4; ++j) {
                    const int m = 2 * ks2 + (j >> 1);
                    const int r = 2 * (j & 1);
                    pk.u[j] = cvt_pk_bf16(__sinf(A[ptt][m][r]), __sinf(A[ptt][m][r + 1]));
                }
                bfr[ptt][ksbase + ks2] = pk.v;
            }
    };
    // one 16KB sub-chunk: 16 frags (ksl 0..1 x ntl 0..7) vs bfr[kq*2+ksl]
    auto chunk_mfma = [&](int slot, int kq, f32x4 (&A)[2][8]) {
        __builtin_amdgcn_s_setprio(1);
#pragma unroll
        for (int ksl = 0; ksl < 2; ++ksl) {
            const bf16x8 bA = bfr[0][kq * 2 + ksl];
            const bf16x8 bB = bfr[1][kq * 2 + ksl];
#pragma unroll
            for (int ntl = 0; ntl < 8; ++ntl) {
                const bf16x8 wfr = frag_at(slot, ksl * 8 + ntl);
                A[0][ntl] = MF(wfr, bA, A[0][ntl]);
                A[1][ntl] = MF(wfr, bB, A[1][ntl]);
            }
        }
        __builtin_amdgcn_s_setprio(0);
    };

    init_half(accA, b0, 0);
    init_half(accB, b0, 8);
    __syncthreads();                    // chunks 0,1 staged

    // ---- interval 0: L0 (chunk 0, 16 frags = nt 0..15) ----
    __builtin_amdgcn_s_setprio(1);
#pragma unroll
    for (int ntl = 0; ntl < 8; ++ntl) {
        const bf16x8 wl = frag_at(0, ntl);
        const bf16x8 wh = frag_at(0, 8 + ntl);
        accA[0][ntl] = MF(wl, af0[0], accA[0][ntl]);
        accA[1][ntl] = MF(wl, af0[1], accA[1][ntl]);
        accB[0][ntl] = MF(wh, af0[0], accB[0][ntl]);
        accB[1][ntl] = MF(wh, af0[1], accB[1][ntl]);
    }
    __builtin_amdgcn_s_setprio(0);
    __syncthreads(); stage(2);

    // ---- hidden layers: 8 intervals each (A0 B0 A1 B1 A2 B2 A3 B3) ----
#define LAYER(cbase, bnext_lo, bnext_hi)                               \
    do {                                                               \
        pack_half(accA, 0); init_half(accA, bnext_lo, 0);              \
        chunk_mfma((cbase) & 1, 0, accA);                              \
        __syncthreads(); stage((cbase) + 2);                           \
        pack_half(accB, 4); init_half(accB, bnext_hi, 8);              \
        chunk_mfma((cbase + 1) & 1, 0, accB);                          \
        __syncthreads(); stage((cbase) + 3);                           \
        chunk_mfma((cbase + 2) & 1, 1, accA);                          \
        __syncthreads(); stage((cbase) + 4);                           \
        chunk_mfma((cbase + 3) & 1, 1, accB);                          \
        __syncthreads(); stage((cbase) + 5);                           \
        chunk_mfma((cbase + 4) & 1, 2, accA);                          \
        __syncthreads(); stage((cbase) + 6);                           \
        chunk_mfma((cbase + 5) & 1, 2, accB);                          \
        __syncthreads(); stage((cbase) + 7);                           \
        chunk_mfma((cbase + 6) & 1, 3, accA);                          \
        __syncthreads(); stage((cbase) + 8);                           \
        chunk_mfma((cbase + 7) & 1, 3, accB);                          \
        __syncthreads(); stage((cbase) + 9);                           \
    } while (0)

    LAYER(1, b1, b1);    // chunks 1..8   (weights W1)
    LAYER(9, b2, b2);    // chunks 9..16  (weights W2)
    LAYER(17, b3, b3);   // chunks 17..24 (weights W3)

    // ---- interval 25 (chunk 25 = Wf) ----
    pack_half(accA, 0);
    pack_half(accB, 4);
    {
        f32x4 fo[2] = {{0, 0, 0, 0}, {0, 0, 0, 0}};
#pragma unroll
        for (int ks = 0; ks < 8; ++ks) {
            const bf16x8 wfr = frag_at(25 & 1, ks);
            fo[0] = MF(wfr, bfr[0][ks], fo[0]);
            fo[1] = MF(wfr, bfr[1][ks], fo[1]);
        }
        if (g == 0) {
#pragma unroll
            for (int ptt = 0; ptt < 2; ++ptt) {
                const long long oi = base + w * 32 + ptt * 16 + p16;
                if (oi < total) {
                    float4 o;
                    o.x = fast_sigmoid(fo[ptt][0] + bfin[0]);
                    o.y = fast_sigmoid(fo[ptt][1] + bfin[1]);
                    o.z = fast_sigmoid(fo[ptt][2] + bfin[2]);
                    o.w = fo[ptt][3] + bfin[3];
                    *(float4*)(out + oi * 4) = o;
                }
            }
        }
    }
}

extern "C" void kernel_launch(void* const* d_in, const int* in_sizes, int n_in,
                              void* d_out, int out_size, void* d_ws, size_t ws_size,
                              hipStream_t stream) {
    const float* points = (const float*)d_in[0];
    const float* vol    = (const float*)d_in[1];
    const float* W0 = (const float*)d_in[2];
    const float* b0 = (const float*)d_in[3];
    const float* W1 = (const float*)d_in[4];
    const float* b1 = (const float*)d_in[5];
    const float* W2 = (const float*)d_in[6];
    const float* b2 = (const float*)d_in[7];
    const float* W3 = (const float*)d_in[8];
    const float* b3 = (const float*)d_in[9];
    const float* Wf = (const float*)d_in[10];
    const float* bf = (const float*)d_in[11];

    const int B = in_sizes[1] / (32 * 32 * 32 * 32);
    const int N = in_sizes[0] / (3 * B);
    const long long total = (long long)B * N;
    const int tiles = (int)((total + 127) / 128);

    ushort* Wstream = (ushort*)d_ws;
    build_frags<<<104, 256, 0, stream>>>(W0, W1, W2, W3, Wf, Wstream);

    const int use_cl = (ws_size >= (size_t)STREAM_BYTES + (size_t)B * 32768 * 32 * 4) ? 1 : 0;
    float* volcl = (float*)((char*)d_ws + STREAM_BYTES);
    if (use_cl) {
        const int nvox = B * 32768;
        vol_chlast<<<(nvox + 255) / 256, 256, 0, stream>>>(vol, volcl, nvox);
    }

    siren_pl<<<tiles, THREADS, 0, stream>>>(
        points, vol, b0, b1, b2, b3, bf, Wstream, volcl, use_cl,
        (float*)d_out, total, N);
}

// Round 10
// 198.963 us; speedup vs baseline: 2.9202x; 2.9202x over previous
//
#include <hip/hip_runtime.h>
#include <math.h>

#define THREADS 256   // 4 waves/block, 32 pts/wave, 128 pts/block; waves fully independent

typedef __attribute__((ext_vector_type(8))) short bf16x8;
typedef __attribute__((ext_vector_type(4))) float f32x4;

// ---------------------------------------------------------------------------
// ws layout: [frag-major weight stream: 448 KB][volcl f32]
// Frag = 1KB (16 neurons x 32 k, 512 bf16). Global frag index f:
//   f 0..15   : L0 (W0 256x32), frag nt=f            (no sigma)
//   f 16..31  : zero pad
//   f 32..159 : W1  (offset 32 + 128*h), per layer 4 sub-chunks of 32:
//       A: nt 0..7 x ks 0..3   B: nt 8..15 x ks 0..3
//       C: nt 0..7 x ks 4..7   D: nt 8..15 x ks 4..7
//     within sub-chunk: idx = ksl*8 + ntl
//   f 160..287: W2      f 288..415: W3
//   f 416..423: Wf (4x256), rows>=4 zeroed, cols sigma-permuted
#define STREAM_BYTES  458752

__device__ __host__ __forceinline__ int sigma_k(int k) {
    // bits [b7 b6 b5 | b4 b3 | b2 b1 | b0] -> [b7 b6 b5 | b2 | b4 b3 | b1 | b0]
    return (k & 0xE1) | ((k & 0x04) << 2) | ((k & 0x18) >> 1) | (k & 0x02);
}

__device__ __forceinline__ ushort f2bf(float f) {
    union { float f; unsigned u; } v; v.f = f;
    unsigned r = v.u + 0x7FFFu + ((v.u >> 16) & 1u);
    return (ushort)(r >> 16);
}

__device__ __forceinline__ float fast_sigmoid(float x) {
    return 1.0f / (1.0f + __expf(-x));
}

__device__ __forceinline__ unsigned cvt_pk_bf16(float lo, float hi) {
    unsigned d;
    asm("v_cvt_pk_bf16_f32 %0, %1, %2" : "=v"(d) : "v"(lo), "v"(hi));
    return d;
}

// ---------------- prep kernels ----------------
__global__ void build_frags(const float* __restrict__ W0,
                            const float* __restrict__ W1,
                            const float* __restrict__ W2,
                            const float* __restrict__ W3,
                            const float* __restrict__ Wf,
                            ushort* __restrict__ stream) {
    const int gid = blockIdx.x * 256 + threadIdx.x;   // 0 .. 28671
    const int f = gid >> 6;
    const int lane = gid & 63;
    const int p16 = lane & 15, g = lane >> 4;
    ushort* dst = stream + (size_t)f * 512 + lane * 8;

    if (f < 16) {                       // L0: W0[f*16+p16][8g+i]
        const float* row = W0 + (size_t)(f * 16 + p16) * 32;
#pragma unroll
        for (int i = 0; i < 8; ++i) dst[i] = f2bf(row[8 * g + i]);
    } else if (f < 32) {
#pragma unroll
        for (int i = 0; i < 8; ++i) dst[i] = 0;
    } else if (f < 416) {
        const int t = f - 32;
        const int h = t >> 7;           // 0,1,2 -> W1,W2,W3
        const int q = (t >> 5) & 3;     // sub-chunk A,B,C,D
        const int ksl = (t >> 3) & 3;
        const int ntl = t & 7;
        const int nt = (q & 1) * 8 + ntl;
        const int ks = (q >> 1) * 4 + ksl;
        const float* W = (h == 0) ? W1 : (h == 1) ? W2 : W3;
        const float* row = W + (size_t)(nt * 16 + p16) * 256;
#pragma unroll
        for (int i = 0; i < 8; ++i) dst[i] = f2bf(row[sigma_k(32 * ks + 8 * g + i)]);
    } else if (f < 424) {               // Wf
        const int ks = f - 416;
        if (p16 < 4) {
            const float* row = Wf + (size_t)p16 * 256;
#pragma unroll
            for (int i = 0; i < 8; ++i) dst[i] = f2bf(row[sigma_k(32 * ks + 8 * g + i)]);
        } else {
#pragma unroll
            for (int i = 0; i < 8; ++i) dst[i] = 0;
        }
    } else {
#pragma unroll
        for (int i = 0; i < 8; ++i) dst[i] = 0;
    }
}

// vol [B][32][32768] f32 -> dst [B*32768][32] f32 (channel-last)
__global__ void vol_chlast(const float* __restrict__ vol, float* __restrict__ dst, int nvox) {
    int v = blockIdx.x * 256 + threadIdx.x;
    if (v >= nvox) return;
    const int b = v >> 15, idx = v & 32767;
    const float* s = vol + (size_t)b * 32 * 32768 + idx;
    float* d = dst + (size_t)v * 32;
#pragma unroll
    for (int c = 0; c < 32; ++c) d[c] = s[(size_t)c * 32768];
}

// ---------------- main fused kernel ----------------
#define MF(a, b, c) __builtin_amdgcn_mfma_f32_16x16x32_bf16((a), (b), (c), 0, 0, 0)

__global__ __launch_bounds__(THREADS, 2)
void siren_pl(const float* __restrict__ points,
              const float* __restrict__ vol,
              const float* __restrict__ b0, const float* __restrict__ b1,
              const float* __restrict__ b2, const float* __restrict__ b3,
              const float* __restrict__ bfin,
              const ushort* __restrict__ Wstream,
              const float* __restrict__ volcl, int use_cl,
              float* __restrict__ out, long long total, int N) {
    const int tid = (int)threadIdx.x;
    const int w = tid >> 6;             // wave 0..3
    const int lane = tid & 63;
    const int p16 = lane & 15;
    const int g = lane >> 4;

    const long long base = (long long)blockIdx.x * 128;

    // per-lane 16B slice of each 1KB frag; frag f at fragp + f*64
    const bf16x8* __restrict__ fragp = (const bf16x8*)Wstream + lane;

    // ---- sample 2 points per lane: channels 8g..8g+7 ----
    bf16x8 af0[2];
    {
#pragma unroll
        for (int ptt = 0; ptt < 2; ++ptt) {
            const long long gidx = base + w * 32 + ptt * 16 + p16;
            const long long gp = gidx < total ? gidx : total - 1;
            const int bi = (int)(gp / N);
            const float* pp = points + gp * 3;
            const float sc = 1.0f / 0.6f;
            const float ix = (pp[0] * sc + 1.0f) * 16.0f - 0.5f;
            const float iy = (pp[1] * sc + 1.0f) * 16.0f - 0.5f;
            const float iz = (pp[2] * sc + 1.0f) * 16.0f - 0.5f;
            const float fx = floorf(ix), fy = floorf(iy), fz = floorf(iz);
            const float wx = ix - fx, wy = iy - fy, wz = iz - fz;
            const int x0 = (int)fminf(fmaxf(fx, 0.0f), 31.0f);
            const int x1 = (int)fminf(fmaxf(fx + 1.0f, 0.0f), 31.0f);
            const int y0 = (int)fminf(fmaxf(fy, 0.0f), 31.0f);
            const int y1 = (int)fminf(fmaxf(fy + 1.0f, 0.0f), 31.0f);
            const int z0 = (int)fminf(fmaxf(fz, 0.0f), 31.0f);
            const int z1 = (int)fminf(fmaxf(fz + 1.0f, 0.0f), 31.0f);
            const int i000 = (z0 * 32 + y0) * 32 + x0, i001 = (z0 * 32 + y0) * 32 + x1;
            const int i010 = (z0 * 32 + y1) * 32 + x0, i011 = (z0 * 32 + y1) * 32 + x1;
            const int i100 = (z1 * 32 + y0) * 32 + x0, i101 = (z1 * 32 + y0) * 32 + x1;
            const int i110 = (z1 * 32 + y1) * 32 + x0, i111 = (z1 * 32 + y1) * 32 + x1;
            const float omx = 1.0f - wx, omy = 1.0f - wy, omz = 1.0f - wz;
            const float w000 = omz * omy * omx, w001 = omz * omy * wx;
            const float w010 = omz * wy * omx,  w011 = omz * wy * wx;
            const float w100 = wz * omy * omx,  w101 = wz * omy * wx;
            const float w110 = wz * wy * omx,   w111 = wz * wy * wx;

            f32x4 a[2];
            if (use_cl) {
                const float* vb = volcl + (size_t)bi * 32768 * 32 + g * 8;
#pragma unroll
                for (int h = 0; h < 2; ++h) {
                    const float* vh = vb + h * 4;
                    a[h]  = w000 * *(const f32x4*)(vh + (size_t)i000 * 32);
                    a[h] += w001 * *(const f32x4*)(vh + (size_t)i001 * 32);
                    a[h] += w010 * *(const f32x4*)(vh + (size_t)i010 * 32);
                    a[h] += w011 * *(const f32x4*)(vh + (size_t)i011 * 32);
                    a[h] += w100 * *(const f32x4*)(vh + (size_t)i100 * 32);
                    a[h] += w101 * *(const f32x4*)(vh + (size_t)i101 * 32);
                    a[h] += w110 * *(const f32x4*)(vh + (size_t)i110 * 32);
                    a[h] += w111 * *(const f32x4*)(vh + (size_t)i111 * 32);
                }
            } else {
                const float* vb = vol + ((size_t)bi * 32 + (size_t)g * 8) * 32768;
#pragma unroll
                for (int c = 0; c < 8; ++c) {
                    const float* vc = vb + (size_t)c * 32768;
                    a[c >> 2][c & 3] =
                        vc[i000] * w000 + vc[i001] * w001 + vc[i010] * w010 + vc[i011] * w011 +
                        vc[i100] * w100 + vc[i101] * w101 + vc[i110] * w110 + vc[i111] * w111;
                }
            }
            union { bf16x8 v; unsigned u[4]; } pk;
            pk.u[0] = cvt_pk_bf16(a[0][0], a[0][1]);
            pk.u[1] = cvt_pk_bf16(a[0][2], a[0][3]);
            pk.u[2] = cvt_pk_bf16(a[1][0], a[1][1]);
            pk.u[3] = cvt_pk_bf16(a[1][2], a[1][3]);
            af0[ptt] = pk.v;
        }
    }

    f32x4 accA[2][8];   // nt 0..7
    f32x4 accB[2][8];   // nt 8..15
    bf16x8 bfr[2][8];   // activations (current layer input), ks=0..7

    auto init_half = [&](f32x4 (&A)[2][8], const float* __restrict__ b, int ntbase) {
#pragma unroll
        for (int m = 0; m < 8; ++m) {
            const f32x4 bv = *(const f32x4*)&b[(ntbase + m) * 16 + 4 * g];
            A[0][m] = bv; A[1][m] = bv;
        }
    };
    auto pack_half = [&](f32x4 (&A)[2][8], int ksbase) {
#pragma unroll
        for (int ptt = 0; ptt < 2; ++ptt)
#pragma unroll
            for (int ks2 = 0; ks2 < 4; ++ks2) {
                union { bf16x8 v; unsigned u[4]; } pk;
#pragma unroll
                for (int j = 0; j < 4; ++j) {
                    const int m = 2 * ks2 + (j >> 1);
                    const int r = 2 * (j & 1);
                    pk.u[j] = cvt_pk_bf16(__sinf(A[ptt][m][r]), __sinf(A[ptt][m][r + 1]));
                }
                bfr[ptt][ksbase + ks2] = pk.v;
            }
    };
    // one 32-frag sub-chunk (ksl 0..3 x ntl 0..7), weights straight from L2
    auto sub_mfma = [&](int fbase, int kh, f32x4 (&A)[2][8]) {
        __builtin_amdgcn_s_setprio(1);
#pragma unroll
        for (int ksl = 0; ksl < 4; ++ksl) {
            const bf16x8 bA = bfr[0][kh * 4 + ksl];
            const bf16x8 bB = bfr[1][kh * 4 + ksl];
#pragma unroll
            for (int ntl = 0; ntl < 8; ++ntl) {
                const bf16x8 wfr = fragp[(fbase + ksl * 8 + ntl) * 64];
                A[0][ntl] = MF(wfr, bA, A[0][ntl]);
                A[1][ntl] = MF(wfr, bB, A[1][ntl]);
            }
        }
        __builtin_amdgcn_s_setprio(0);
    };

    // ---- L0: frags 0..15 ----
    init_half(accA, b0, 0);
    init_half(accB, b0, 8);
    __builtin_amdgcn_s_setprio(1);
#pragma unroll
    for (int ntl = 0; ntl < 8; ++ntl) {
        const bf16x8 wl = fragp[ntl * 64];
        const bf16x8 wh = fragp[(8 + ntl) * 64];
#pragma unroll
        for (int ptt = 0; ptt < 2; ++ptt) {
            accA[ptt][ntl] = MF(wl, af0[ptt], accA[ptt][ntl]);
            accB[ptt][ntl] = MF(wh, af0[ptt], accB[ptt][ntl]);
        }
    }
    __builtin_amdgcn_s_setprio(0);

    // ---- hidden layers: frag bases 32, 160, 288; sub-chunks A,B,C,D ----
#define LAYER(F, BNEXT)                                                \
    do {                                                               \
        pack_half(accA, 0); init_half(accA, BNEXT, 0);                 \
        sub_mfma((F), 0, accA);                                        \
        pack_half(accB, 4); init_half(accB, BNEXT, 8);                 \
        sub_mfma((F) + 32, 0, accB);                                   \
        sub_mfma((F) + 64, 1, accA);                                   \
        sub_mfma((F) + 96, 1, accB);                                   \
    } while (0)

    LAYER(32, b1);
    LAYER(160, b2);
    LAYER(288, b3);

    // ---- final: frags 416..423 (Wf) ----
    pack_half(accA, 0);
    pack_half(accB, 4);
    {
        f32x4 fo[2] = {{0, 0, 0, 0}, {0, 0, 0, 0}};
#pragma unroll
        for (int ks = 0; ks < 8; ++ks) {
            const bf16x8 wfr = fragp[(416 + ks) * 64];
            fo[0] = MF(wfr, bfr[0][ks], fo[0]);
            fo[1] = MF(wfr, bfr[1][ks], fo[1]);
        }
        if (g == 0) {
#pragma unroll
            for (int ptt = 0; ptt < 2; ++ptt) {
                const long long oi = base + w * 32 + ptt * 16 + p16;
                if (oi < total) {
                    float4 o;
                    o.x = fast_sigmoid(fo[ptt][0] + bfin[0]);
                    o.y = fast_sigmoid(fo[ptt][1] + bfin[1]);
                    o.z = fast_sigmoid(fo[ptt][2] + bfin[2]);
                    o.w = fo[ptt][3] + bfin[3];
                    *(float4*)(out + oi * 4) = o;
                }
            }
        }
    }
}

extern "C" void kernel_launch(void* const* d_in, const int* in_sizes, int n_in,
                              void* d_out, int out_size, void* d_ws, size_t ws_size,
                              hipStream_t stream) {
    const float* points = (const float*)d_in[0];
    const float* vol    = (const float*)d_in[1];
    const float* W0 = (const float*)d_in[2];
    const float* b0 = (const float*)d_in[3];
    const float* W1 = (const float*)d_in[4];
    const float* b1 = (const float*)d_in[5];
    const float* W2 = (const float*)d_in[6];
    const float* b2 = (const float*)d_in[7];
    const float* W3 = (const float*)d_in[8];
    const float* b3 = (const float*)d_in[9];
    const float* Wf = (const float*)d_in[10];
    const float* bf = (const float*)d_in[11];

    const int B = in_sizes[1] / (32 * 32 * 32 * 32);
    const int N = in_sizes[0] / (3 * B);
    const long long total = (long long)B * N;
    const int tiles = (int)((total + 127) / 128);

    ushort* Wstream = (ushort*)d_ws;
    build_frags<<<112, 256, 0, stream>>>(W0, W1, W2, W3, Wf, Wstream);

    const int use_cl = (ws_size >= (size_t)STREAM_BYTES + (size_t)B * 32768 * 32 * 4) ? 1 : 0;
    float* volcl = (float*)((char*)d_ws + STREAM_BYTES);
    if (use_cl) {
        const int nvox = B * 32768;
        vol_chlast<<<(nvox + 255) / 256, 256, 0, stream>>>(vol, volcl, nvox);
    }

    siren_pl<<<tiles, THREADS, 0, stream>>>(
        points, vol, b0, b1, b2, b3, bf, Wstream, volcl, use_cl,
        (float*)d_out, total, N);
}

// Round 11
// 107.052 us; speedup vs baseline: 5.4274x; 1.8586x over previous
//
#include <hip/hip_runtime.h>
#include <math.h>

#define THREADS 256   // 4 waves/block, 32 pts/wave, 128 pts/block

typedef __attribute__((ext_vector_type(8))) short bf16x8;
typedef __attribute__((ext_vector_type(4))) float f32x4;

// ---------------------------------------------------------------------------
// ws layout: [frag-major weight stream: 26 chunks x 16KB = 425984 B][volcl f32]
// Frag = 1KB (16 neurons x 32 k, 512 bf16). 416 frags total, 16 per chunk.
//   chunk 0       : L0 (W0 256x32): frags nt=0..15
//   chunks 1..24  : 3 hidden layers x 8 sub-chunks, order per layer:
//       A0 B0 A1 B1 A2 B2 A3 B3   (A: nt 0..7, B: nt 8..15; kq = ks pair)
//     within sub-chunk: idx = ksl*8 + ntl  (ksl 0..1, ntl 0..7)
//   chunk 25      : Wf frags ks=0..7 (rows>=4 zero) + 8 zero frags
#define NCHUNK 26
#define STREAM_BYTES (NCHUNK * 16384)

__device__ __host__ __forceinline__ int sigma_k(int k) {
    // bits [b7 b6 b5 | b4 b3 | b2 b1 | b0] -> [b7 b6 b5 | b2 | b4 b3 | b1 | b0]
    return (k & 0xE1) | ((k & 0x04) << 2) | ((k & 0x18) >> 1) | (k & 0x02);
}

__device__ __forceinline__ ushort f2bf(float f) {
    union { float f; unsigned u; } v; v.f = f;
    unsigned r = v.u + 0x7FFFu + ((v.u >> 16) & 1u);
    return (ushort)(r >> 16);
}

__device__ __forceinline__ float fast_sigmoid(float x) {
    return 1.0f / (1.0f + __expf(-x));
}

__device__ __forceinline__ unsigned cvt_pk_bf16(float lo, float hi) {
    unsigned d;
    asm("v_cvt_pk_bf16_f32 %0, %1, %2" : "=v"(d) : "v"(lo), "v"(hi));
    return d;
}

// ---------------- prep kernels ----------------
__global__ void build_frags(const float* __restrict__ W0,
                            const float* __restrict__ W1,
                            const float* __restrict__ W2,
                            const float* __restrict__ W3,
                            const float* __restrict__ Wf,
                            ushort* __restrict__ stream) {
    const int gid = blockIdx.x * 256 + threadIdx.x;   // 0 .. 26623
    const int f = gid >> 6;                            // frag 0..415
    if (f >= 416) return;
    const int lane = gid & 63;
    const int p16 = lane & 15, g = lane >> 4;
    ushort* dst = stream + (size_t)f * 512 + lane * 8;

    if (f < 16) {                       // L0: W0[f*16+p16][8g+i]
        const float* row = W0 + (size_t)(f * 16 + p16) * 32;
#pragma unroll
        for (int i = 0; i < 8; ++i) dst[i] = f2bf(row[8 * g + i]);
    } else if (f < 400) {
        const int t = f - 16;
        const int h = t >> 7;           // layer: 0,1,2 -> W1,W2,W3
        const int r = t & 127;
        const int sub = r >> 4;         // 0..7 = A0 B0 A1 B1 A2 B2 A3 B3
        const int idx = r & 15;
        const int q = sub & 1;          // 0=A(nt0..7) 1=B(nt8..15)
        const int kq = sub >> 1;        // ks pair 0..3
        const int ksl = idx >> 3;       // 0..1
        const int ntl = idx & 7;
        const int nt = q * 8 + ntl;
        const int ks = kq * 2 + ksl;
        const float* W = (h == 0) ? W1 : (h == 1) ? W2 : W3;
        const float* row = W + (size_t)(nt * 16 + p16) * 256;
#pragma unroll
        for (int i = 0; i < 8; ++i) dst[i] = f2bf(row[sigma_k(32 * ks + 8 * g + i)]);
    } else if (f < 408) {               // Wf
        const int ks = f - 400;
        if (p16 < 4) {
            const float* row = Wf + (size_t)p16 * 256;
#pragma unroll
            for (int i = 0; i < 8; ++i) dst[i] = f2bf(row[sigma_k(32 * ks + 8 * g + i)]);
        } else {
#pragma unroll
            for (int i = 0; i < 8; ++i) dst[i] = 0;
        }
    } else {
#pragma unroll
        for (int i = 0; i < 8; ++i) dst[i] = 0;
    }
}

// vol [B][32][32768] f32 -> dst [B*32768][32] f32 (channel-last)
__global__ void vol_chlast(const float* __restrict__ vol, float* __restrict__ dst, int nvox) {
    int v = blockIdx.x * 256 + threadIdx.x;
    if (v >= nvox) return;
    const int b = v >> 15, idx = v & 32767;
    const float* s = vol + (size_t)b * 32 * 32768 + idx;
    float* d = dst + (size_t)v * 32;
#pragma unroll
    for (int c = 0; c < 32; ++c) d[c] = s[(size_t)c * 32768];
}

// ---------------- main fused kernel ----------------
#define MF(a, b, c) __builtin_amdgcn_mfma_f32_16x16x32_bf16((a), (b), (c), 0, 0, 0)

// NOTE: (256,2) NOT (256,4): the latter caps VGPR at 64 (measured r9) and
// spills ~190 live regs catastrophically. With VGPR=128 (measured r7) the
// HW itself allows 4 waves/SIMD; 32KB LDS/block then gives 4 blocks/CU.
__global__ __launch_bounds__(THREADS, 2)
void siren_pl(const float* __restrict__ points,
              const float* __restrict__ vol,
              const float* __restrict__ b0, const float* __restrict__ b1,
              const float* __restrict__ b2, const float* __restrict__ b3,
              const float* __restrict__ bfin,
              const ushort* __restrict__ Wstream,
              const float* __restrict__ volcl, int use_cl,
              float* __restrict__ out, long long total, int N) {
    __shared__ ushort ring[2][8192];    // 2 x 16KB -> 32KB/block

    const int tid = (int)threadIdx.x;
    const int w = tid >> 6;             // wave 0..3
    const int lane = tid & 63;
    const int p16 = lane & 15;
    const int g = lane >> 4;

    const long long base = (long long)blockIdx.x * 128;

    auto stage = [&](int c) {
        if (c >= NCHUNK) return;
        const ushort* src = Wstream + (size_t)c * 8192;
        ushort* dstbase = &ring[c & 1][0];
#pragma unroll
        for (int q = 0; q < 4; ++q) {
            const int off = (q * 4 + w) * 512;   // elements; wave-uniform
            __builtin_amdgcn_global_load_lds(
                (const __attribute__((address_space(1))) unsigned int*)(src + off + lane * 8),
                (__attribute__((address_space(3))) unsigned int*)(dstbase + off),
                16, 0, 0);
        }
    };
    stage(0);
    stage(1);

    // ---- sample 2 points per lane: channels 8g..8g+7 ----
    bf16x8 af0[2];
    {
#pragma unroll
        for (int ptt = 0; ptt < 2; ++ptt) {
            const long long gidx = base + w * 32 + ptt * 16 + p16;
            const long long gp = gidx < total ? gidx : total - 1;
            const int bi = (int)(gp / N);
            const float* pp = points + gp * 3;
            const float sc = 1.0f / 0.6f;
            const float ix = (pp[0] * sc + 1.0f) * 16.0f - 0.5f;
            const float iy = (pp[1] * sc + 1.0f) * 16.0f - 0.5f;
            const float iz = (pp[2] * sc + 1.0f) * 16.0f - 0.5f;
            const float fx = floorf(ix), fy = floorf(iy), fz = floorf(iz);
            const float wx = ix - fx, wy = iy - fy, wz = iz - fz;
            const int x0 = (int)fminf(fmaxf(fx, 0.0f), 31.0f);
            const int x1 = (int)fminf(fmaxf(fx + 1.0f, 0.0f), 31.0f);
            const int y0 = (int)fminf(fmaxf(fy, 0.0f), 31.0f);
            const int y1 = (int)fminf(fmaxf(fy + 1.0f, 0.0f), 31.0f);
            const int z0 = (int)fminf(fmaxf(fz, 0.0f), 31.0f);
            const int z1 = (int)fminf(fmaxf(fz + 1.0f, 0.0f), 31.0f);
            const int i000 = (z0 * 32 + y0) * 32 + x0, i001 = (z0 * 32 + y0) * 32 + x1;
            const int i010 = (z0 * 32 + y1) * 32 + x0, i011 = (z0 * 32 + y1) * 32 + x1;
            const int i100 = (z1 * 32 + y0) * 32 + x0, i101 = (z1 * 32 + y0) * 32 + x1;
            const int i110 = (z1 * 32 + y1) * 32 + x0, i111 = (z1 * 32 + y1) * 32 + x1;
            const float omx = 1.0f - wx, omy = 1.0f - wy, omz = 1.0f - wz;
            const float w000 = omz * omy * omx, w001 = omz * omy * wx;
            const float w010 = omz * wy * omx,  w011 = omz * wy * wx;
            const float w100 = wz * omy * omx,  w101 = wz * omy * wx;
            const float w110 = wz * wy * omx,   w111 = wz * wy * wx;

            f32x4 a[2];
            if (use_cl) {
                const float* vb = volcl + (size_t)bi * 32768 * 32 + g * 8;
#pragma unroll
                for (int h = 0; h < 2; ++h) {
                    const float* vh = vb + h * 4;
                    a[h]  = w000 * *(const f32x4*)(vh + (size_t)i000 * 32);
                    a[h] += w001 * *(const f32x4*)(vh + (size_t)i001 * 32);
                    a[h] += w010 * *(const f32x4*)(vh + (size_t)i010 * 32);
                    a[h] += w011 * *(const f32x4*)(vh + (size_t)i011 * 32);
                    a[h] += w100 * *(const f32x4*)(vh + (size_t)i100 * 32);
                    a[h] += w101 * *(const f32x4*)(vh + (size_t)i101 * 32);
                    a[h] += w110 * *(const f32x4*)(vh + (size_t)i110 * 32);
                    a[h] += w111 * *(const f32x4*)(vh + (size_t)i111 * 32);
                }
            } else {
                const float* vb = vol + ((size_t)bi * 32 + (size_t)g * 8) * 32768;
#pragma unroll
                for (int c = 0; c < 8; ++c) {
                    const float* vc = vb + (size_t)c * 32768;
                    a[c >> 2][c & 3] =
                        vc[i000] * w000 + vc[i001] * w001 + vc[i010] * w010 + vc[i011] * w011 +
                        vc[i100] * w100 + vc[i101] * w101 + vc[i110] * w110 + vc[i111] * w111;
                }
            }
            union { bf16x8 v; unsigned u[4]; } pk;
            pk.u[0] = cvt_pk_bf16(a[0][0], a[0][1]);
            pk.u[1] = cvt_pk_bf16(a[0][2], a[0][3]);
            pk.u[2] = cvt_pk_bf16(a[1][0], a[1][1]);
            pk.u[3] = cvt_pk_bf16(a[1][2], a[1][3]);
            af0[ptt] = pk.v;
        }
    }

    f32x4 accA[2][8];   // nt 0..7
    f32x4 accB[2][8];   // nt 8..15
    bf16x8 bfr[2][8];   // activations, frag ks=0..7

    auto frag_at = [&](int slot, int idx) -> bf16x8 {
        return *(const bf16x8*)&ring[slot][idx * 512 + lane * 8];
    };
    auto init_half = [&](f32x4 (&A)[2][8], const float* __restrict__ b, int ntbase) {
#pragma unroll
        for (int m = 0; m < 8; ++m) {
            const f32x4 bv = *(const f32x4*)&b[(ntbase + m) * 16 + 4 * g];
            A[0][m] = bv; A[1][m] = bv;
        }
    };
    // pack 8 acc tiles (one nt-half) into bfr[ksbase..ksbase+3]
    auto pack_half = [&](f32x4 (&A)[2][8], int ksbase) {
#pragma unroll
        for (int ptt = 0; ptt < 2; ++ptt)
#pragma unroll
            for (int ks2 = 0; ks2 < 4; ++ks2) {
                union { bf16x8 v; unsigned u[4]; } pk;
#pragma unroll
                for (int j = 0; j < 4; ++j) {
                    const int m = 2 * ks2 + (j >> 1);
                    const int r = 2 * (j & 1);
                    pk.u[j] = cvt_pk_bf16(__sinf(A[ptt][m][r]), __sinf(A[ptt][m][r + 1]));
                }
                bfr[ptt][ksbase + ks2] = pk.v;
            }
    };
    // one 16KB sub-chunk: 16 frags (ksl 0..1 x ntl 0..7) vs bfr[kq*2+ksl]
    auto chunk_mfma = [&](int slot, int kq, f32x4 (&A)[2][8]) {
        __builtin_amdgcn_s_setprio(1);
#pragma unroll
        for (int ksl = 0; ksl < 2; ++ksl) {
            const bf16x8 bA = bfr[0][kq * 2 + ksl];
            const bf16x8 bB = bfr[1][kq * 2 + ksl];
#pragma unroll
            for (int ntl = 0; ntl < 8; ++ntl) {
                const bf16x8 wfr = frag_at(slot, ksl * 8 + ntl);
                A[0][ntl] = MF(wfr, bA, A[0][ntl]);
                A[1][ntl] = MF(wfr, bB, A[1][ntl]);
            }
        }
        __builtin_amdgcn_s_setprio(0);
    };

    init_half(accA, b0, 0);
    init_half(accB, b0, 8);
    __syncthreads();                    // chunks 0,1 staged

    // ---- interval 0: L0 (chunk 0, 16 frags = nt 0..15) ----
    __builtin_amdgcn_s_setprio(1);
#pragma unroll
    for (int ntl = 0; ntl < 8; ++ntl) {
        const bf16x8 wl = frag_at(0, ntl);
        const bf16x8 wh = frag_at(0, 8 + ntl);
        accA[0][ntl] = MF(wl, af0[0], accA[0][ntl]);
        accA[1][ntl] = MF(wl, af0[1], accA[1][ntl]);
        accB[0][ntl] = MF(wh, af0[0], accB[0][ntl]);
        accB[1][ntl] = MF(wh, af0[1], accB[1][ntl]);
    }
    __builtin_amdgcn_s_setprio(0);
    __syncthreads(); stage(2);

    // ---- hidden layers: 8 intervals each (A0 B0 A1 B1 A2 B2 A3 B3) ----
#define LAYER(cbase, bnext_lo, bnext_hi)                               \
    do {                                                               \
        pack_half(accA, 0); init_half(accA, bnext_lo, 0);              \
        chunk_mfma((cbase) & 1, 0, accA);                              \
        __syncthreads(); stage((cbase) + 2);                           \
        pack_half(accB, 4); init_half(accB, bnext_hi, 8);              \
        chunk_mfma((cbase + 1) & 1, 0, accB);                          \
        __syncthreads(); stage((cbase) + 3);                           \
        chunk_mfma((cbase + 2) & 1, 1, accA);                          \
        __syncthreads(); stage((cbase) + 4);                           \
        chunk_mfma((cbase + 3) & 1, 1, accB);                          \
        __syncthreads(); stage((cbase) + 5);                           \
        chunk_mfma((cbase + 4) & 1, 2, accA);                          \
        __syncthreads(); stage((cbase) + 6);                           \
        chunk_mfma((cbase + 5) & 1, 2, accB);                          \
        __syncthreads(); stage((cbase) + 7);                           \
        chunk_mfma((cbase + 6) & 1, 3, accA);                          \
        __syncthreads(); stage((cbase) + 8);                           \
        chunk_mfma((cbase + 7) & 1, 3, accB);                          \
        __syncthreads(); stage((cbase) + 9);                           \
    } while (0)

    LAYER(1, b1, b1);    // chunks 1..8   (weights W1)
    LAYER(9, b2, b2);    // chunks 9..16  (weights W2)
    LAYER(17, b3, b3);   // chunks 17..24 (weights W3)

    // ---- interval 25 (chunk 25 = Wf) ----
    pack_half(accA, 0);
    pack_half(accB, 4);
    {
        f32x4 fo[2] = {{0, 0, 0, 0}, {0, 0, 0, 0}};
#pragma unroll
        for (int ks = 0; ks < 8; ++ks) {
            const bf16x8 wfr = frag_at(25 & 1, ks);
            fo[0] = MF(wfr, bfr[0][ks], fo[0]);
            fo[1] = MF(wfr, bfr[1][ks], fo[1]);
        }
        if (g == 0) {
#pragma unroll
            for (int ptt = 0; ptt < 2; ++ptt) {
                const long long oi = base + w * 32 + ptt * 16 + p16;
                if (oi < total) {
                    float4 o;
                    o.x = fast_sigmoid(fo[ptt][0] + bfin[0]);
                    o.y = fast_sigmoid(fo[ptt][1] + bfin[1]);
                    o.z = fast_sigmoid(fo[ptt][2] + bfin[2]);
                    o.w = fo[ptt][3] + bfin[3];
                    *(float4*)(out + oi * 4) = o;
                }
            }
        }
    }
}

extern "C" void kernel_launch(void* const* d_in, const int* in_sizes, int n_in,
                              void* d_out, int out_size, void* d_ws, size_t ws_size,
                              hipStream_t stream) {
    const float* points = (const float*)d_in[0];
    const float* vol    = (const float*)d_in[1];
    const float* W0 = (const float*)d_in[2];
    const float* b0 = (const float*)d_in[3];
    const float* W1 = (const float*)d_in[4];
    const float* b1 = (const float*)d_in[5];
    const float* W2 = (const float*)d_in[6];
    const float* b2 = (const float*)d_in[7];
    const float* W3 = (const float*)d_in[8];
    const float* b3 = (const float*)d_in[9];
    const float* Wf = (const float*)d_in[10];
    const float* bf = (const float*)d_in[11];

    const int B = in_sizes[1] / (32 * 32 * 32 * 32);
    const int N = in_sizes[0] / (3 * B);
    const long long total = (long long)B * N;
    const int tiles = (int)((total + 127) / 128);

    ushort* Wstream = (ushort*)d_ws;
    build_frags<<<104, 256, 0, stream>>>(W0, W1, W2, W3, Wf, Wstream);

    const int use_cl = (ws_size >= (size_t)STREAM_BYTES + (size_t)B * 32768 * 32 * 4) ? 1 : 0;
    float* volcl = (float*)((char*)d_ws + STREAM_BYTES);
    if (use_cl) {
        const int nvox = B * 32768;
        vol_chlast<<<(nvox + 255) / 256, 256, 0, stream>>>(vol, volcl, nvox);
    }

    siren_pl<<<tiles, THREADS, 0, stream>>>(
        points, vol, b0, b1, b2, b3, bf, Wstream, volcl, use_cl,
        (float*)d_out, total, N);
}

// Round 12
// 106.776 us; speedup vs baseline: 5.4415x; 1.0026x over previous
//
#include <hip/hip_runtime.h>
#include <math.h>

#define THREADS 256   // 4 waves/block, 32 pts/wave, 128 pts/block

typedef __attribute__((ext_vector_type(8))) short bf16x8;
typedef __attribute__((ext_vector_type(4))) float f32x4;

#define INV2PI 0.15915494309189535f

// ---------------------------------------------------------------------------
// ws layout: [stream 26x16KB][scaled biases 4x256 f32 = 4KB][volcl f32]
// Frag = 1KB. 416 frags, 16/chunk.
//   chunk 0      : L0 (W0 256x32, x1/2pi): frags nt=0..15
//   chunks 1..24 : per layer 8 chunks in order A0 A1 A2 A3 B0 B1 B2 B3
//       (A: nt 0..7, B: nt 8..15; kq 0..3 = ks pair; x1/2pi)
//     within chunk: idx = ksl*8 + ntl  (ksl 0..1, ntl 0..7)
//   chunk 25     : Wf frags ks=0..7 (rows>=4 zero, UNscaled) + 8 zero frags
#define NCHUNK 26
#define STREAM_BYTES (NCHUNK * 16384)
#define SBIAS_BYTES 4096

__device__ __host__ __forceinline__ int sigma_k(int k) {
    // bits [b7 b6 b5 | b4 b3 | b2 b1 | b0] -> [b7 b6 b5 | b2 | b4 b3 | b1 | b0]
    return (k & 0xE1) | ((k & 0x04) << 2) | ((k & 0x18) >> 1) | (k & 0x02);
}

__device__ __forceinline__ ushort f2bf(float f) {
    union { float f; unsigned u; } v; v.f = f;
    unsigned r = v.u + 0x7FFFu + ((v.u >> 16) & 1u);
    return (ushort)(r >> 16);
}

__device__ __forceinline__ float fast_sigmoid(float x) {
    return 1.0f / (1.0f + __expf(-x));
}

__device__ __forceinline__ unsigned cvt_pk_bf16(float lo, float hi) {
    unsigned d;
    asm("v_cvt_pk_bf16_f32 %0, %1, %2" : "=v"(d) : "v"(lo), "v"(hi));
    return d;
}

// hardware sin, input in REVOLUTIONS (weights pre-scaled by 1/2pi)
__device__ __forceinline__ float hw_sin(float x) {
    float r;
    asm("v_sin_f32 %0, %1" : "=v"(r) : "v"(x));
    return r;
}

// ---------------- prep kernels ----------------
__global__ void build_frags(const float* __restrict__ W0,
                            const float* __restrict__ W1,
                            const float* __restrict__ W2,
                            const float* __restrict__ W3,
                            const float* __restrict__ Wf,
                            ushort* __restrict__ stream) {
    const int gid = blockIdx.x * 256 + threadIdx.x;   // 0 .. 26623
    const int f = gid >> 6;                            // frag 0..415
    if (f >= 416) return;
    const int lane = gid & 63;
    const int p16 = lane & 15, g = lane >> 4;
    ushort* dst = stream + (size_t)f * 512 + lane * 8;

    if (f < 16) {                       // L0: W0[f*16+p16][8g+i] * 1/2pi
        const float* row = W0 + (size_t)(f * 16 + p16) * 32;
#pragma unroll
        for (int i = 0; i < 8; ++i) dst[i] = f2bf(row[8 * g + i] * INV2PI);
    } else if (f < 400) {
        const int t = f - 16;
        const int h = t >> 7;           // layer: 0,1,2 -> W1,W2,W3
        const int r = t & 127;
        const int sub = r >> 4;         // 0..7 = A0 A1 A2 A3 B0 B1 B2 B3
        const int idx = r & 15;
        const int q = sub >> 2;         // 0=A(nt0..7) 1=B(nt8..15)
        const int kq = sub & 3;         // ks pair 0..3
        const int ksl = idx >> 3;       // 0..1
        const int ntl = idx & 7;
        const int nt = q * 8 + ntl;
        const int ks = kq * 2 + ksl;
        const float* W = (h == 0) ? W1 : (h == 1) ? W2 : W3;
        const float* row = W + (size_t)(nt * 16 + p16) * 256;
#pragma unroll
        for (int i = 0; i < 8; ++i) dst[i] = f2bf(row[sigma_k(32 * ks + 8 * g + i)] * INV2PI);
    } else if (f < 408) {               // Wf (unscaled)
        const int ks = f - 400;
        if (p16 < 4) {
            const float* row = Wf + (size_t)p16 * 256;
#pragma unroll
            for (int i = 0; i < 8; ++i) dst[i] = f2bf(row[sigma_k(32 * ks + 8 * g + i)]);
        } else {
#pragma unroll
            for (int i = 0; i < 8; ++i) dst[i] = 0;
        }
    } else {
#pragma unroll
        for (int i = 0; i < 8; ++i) dst[i] = 0;
    }
}

__global__ void scale_biases(const float* __restrict__ b0, const float* __restrict__ b1,
                             const float* __restrict__ b2, const float* __restrict__ b3,
                             float* __restrict__ sb) {
    const int i = blockIdx.x * 256 + threadIdx.x;   // 0..1023
    const int l = i >> 8, j = i & 255;
    const float* b = (l == 0) ? b0 : (l == 1) ? b1 : (l == 2) ? b2 : b3;
    sb[i] = b[j] * INV2PI;
}

// vol [B][32][32768] f32 -> dst [B*32768][32] f32 (channel-last)
__global__ void vol_chlast(const float* __restrict__ vol, float* __restrict__ dst, int nvox) {
    int v = blockIdx.x * 256 + threadIdx.x;
    if (v >= nvox) return;
    const int b = v >> 15, idx = v & 32767;
    const float* s = vol + (size_t)b * 32 * 32768 + idx;
    float* d = dst + (size_t)v * 32;
#pragma unroll
    for (int c = 0; c < 32; ++c) d[c] = s[(size_t)c * 32768];
}

// ---------------- main fused kernel ----------------
#define MF(a, b, c) __builtin_amdgcn_mfma_f32_16x16x32_bf16((a), (b), (c), 0, 0, 0)

// (256,2): VGPR cap 256. Total per-wave regs (arch+acc) ~176 -> 2 waves/SIMD
// is the hard ceiling for this algorithm; schedule for within-wave overlap.
__global__ __launch_bounds__(THREADS, 2)
void siren_pl(const float* __restrict__ points,
              const float* __restrict__ vol,
              const float* __restrict__ bfin,
              const ushort* __restrict__ Wstream,
              const float* __restrict__ sb,       // scaled biases [4][256]
              const float* __restrict__ volcl, int use_cl,
              float* __restrict__ out, long long total, int N) {
    __shared__ ushort ring[2][8192];    // 2 x 16KB

    const int tid = (int)threadIdx.x;
    const int w = tid >> 6;             // wave 0..3
    const int lane = tid & 63;
    const int p16 = lane & 15;
    const int g = lane >> 4;

    const long long base = (long long)blockIdx.x * 128;

    auto stage = [&](int c) {
        if (c >= NCHUNK) return;
        const ushort* src = Wstream + (size_t)c * 8192;
        ushort* dstbase = &ring[c & 1][0];
#pragma unroll
        for (int q = 0; q < 4; ++q) {
            const int off = (q * 4 + w) * 512;   // elements; wave-uniform
            __builtin_amdgcn_global_load_lds(
                (const __attribute__((address_space(1))) unsigned int*)(src + off + lane * 8),
                (__attribute__((address_space(3))) unsigned int*)(dstbase + off),
                16, 0, 0);
        }
    };
    stage(0);
    stage(1);

    // ---- sample 2 points per lane: channels 8g..8g+7 ----
    bf16x8 af0[2];
    {
#pragma unroll
        for (int ptt = 0; ptt < 2; ++ptt) {
            const long long gidx = base + w * 32 + ptt * 16 + p16;
            const long long gp = gidx < total ? gidx : total - 1;
            const int bi = (int)(gp / N);
            const float* pp = points + gp * 3;
            const float sc = 1.0f / 0.6f;
            const float ix = (pp[0] * sc + 1.0f) * 16.0f - 0.5f;
            const float iy = (pp[1] * sc + 1.0f) * 16.0f - 0.5f;
            const float iz = (pp[2] * sc + 1.0f) * 16.0f - 0.5f;
            const float fx = floorf(ix), fy = floorf(iy), fz = floorf(iz);
            const float wx = ix - fx, wy = iy - fy, wz = iz - fz;
            const int x0 = (int)fminf(fmaxf(fx, 0.0f), 31.0f);
            const int x1 = (int)fminf(fmaxf(fx + 1.0f, 0.0f), 31.0f);
            const int y0 = (int)fminf(fmaxf(fy, 0.0f), 31.0f);
            const int y1 = (int)fminf(fmaxf(fy + 1.0f, 0.0f), 31.0f);
            const int z0 = (int)fminf(fmaxf(fz, 0.0f), 31.0f);
            const int z1 = (int)fminf(fmaxf(fz + 1.0f, 0.0f), 31.0f);
            const int i000 = (z0 * 32 + y0) * 32 + x0, i001 = (z0 * 32 + y0) * 32 + x1;
            const int i010 = (z0 * 32 + y1) * 32 + x0, i011 = (z0 * 32 + y1) * 32 + x1;
            const int i100 = (z1 * 32 + y0) * 32 + x0, i101 = (z1 * 32 + y0) * 32 + x1;
            const int i110 = (z1 * 32 + y1) * 32 + x0, i111 = (z1 * 32 + y1) * 32 + x1;
            const float omx = 1.0f - wx, omy = 1.0f - wy, omz = 1.0f - wz;
            const float w000 = omz * omy * omx, w001 = omz * omy * wx;
            const float w010 = omz * wy * omx,  w011 = omz * wy * wx;
            const float w100 = wz * omy * omx,  w101 = wz * omy * wx;
            const float w110 = wz * wy * omx,   w111 = wz * wy * wx;

            f32x4 a[2];
            if (use_cl) {
                const float* vb = volcl + (size_t)bi * 32768 * 32 + g * 8;
#pragma unroll
                for (int h = 0; h < 2; ++h) {
                    const float* vh = vb + h * 4;
                    a[h]  = w000 * *(const f32x4*)(vh + (size_t)i000 * 32);
                    a[h] += w001 * *(const f32x4*)(vh + (size_t)i001 * 32);
                    a[h] += w010 * *(const f32x4*)(vh + (size_t)i010 * 32);
                    a[h] += w011 * *(const f32x4*)(vh + (size_t)i011 * 32);
                    a[h] += w100 * *(const f32x4*)(vh + (size_t)i100 * 32);
                    a[h] += w101 * *(const f32x4*)(vh + (size_t)i101 * 32);
                    a[h] += w110 * *(const f32x4*)(vh + (size_t)i110 * 32);
                    a[h] += w111 * *(const f32x4*)(vh + (size_t)i111 * 32);
                }
            } else {
                const float* vb = vol + ((size_t)bi * 32 + (size_t)g * 8) * 32768;
#pragma unroll
                for (int c = 0; c < 8; ++c) {
                    const float* vc = vb + (size_t)c * 32768;
                    a[c >> 2][c & 3] =
                        vc[i000] * w000 + vc[i001] * w001 + vc[i010] * w010 + vc[i011] * w011 +
                        vc[i100] * w100 + vc[i101] * w101 + vc[i110] * w110 + vc[i111] * w111;
                }
            }
            union { bf16x8 v; unsigned u[4]; } pk;
            pk.u[0] = cvt_pk_bf16(a[0][0], a[0][1]);
            pk.u[1] = cvt_pk_bf16(a[0][2], a[0][3]);
            pk.u[2] = cvt_pk_bf16(a[1][0], a[1][1]);
            pk.u[3] = cvt_pk_bf16(a[1][2], a[1][3]);
            af0[ptt] = pk.v;
        }
    }

    f32x4 accA[2][8];   // nt 0..7
    f32x4 accB[2][8];   // nt 8..15
    bf16x8 bfr[2][8];   // activations, ks=0..7

    auto frag_at = [&](int slot, int idx) -> bf16x8 {
        return *(const bf16x8*)&ring[slot][idx * 512 + lane * 8];
    };
    auto init_half = [&](f32x4 (&A)[2][8], const float* __restrict__ b, int ntbase) {
#pragma unroll
        for (int m = 0; m < 8; ++m) {
            const f32x4 bv = *(const f32x4*)&b[(ntbase + m) * 16 + 4 * g];
            A[0][m] = bv; A[1][m] = bv;
        }
    };
    // pack 8 acc tiles (one nt-half) into bfr[ksbase..ksbase+3]; acc is preact/2pi
    auto pack_half = [&](f32x4 (&A)[2][8], int ksbase) {
#pragma unroll
        for (int ptt = 0; ptt < 2; ++ptt)
#pragma unroll
            for (int ks2 = 0; ks2 < 4; ++ks2) {
                union { bf16x8 v; unsigned u[4]; } pk;
#pragma unroll
                for (int j = 0; j < 4; ++j) {
                    const int m = 2 * ks2 + (j >> 1);
                    const int r = 2 * (j & 1);
                    pk.u[j] = cvt_pk_bf16(hw_sin(A[ptt][m][r]), hw_sin(A[ptt][m][r + 1]));
                }
                bfr[ptt][ksbase + ks2] = pk.v;
            }
    };
    // one 16KB chunk: 16 frags (ksl 0..1 x ntl 0..7) vs bfr[kq*2+ksl]
    auto chunk_mfma = [&](int slot, int kq, f32x4 (&A)[2][8]) {
        __builtin_amdgcn_s_setprio(1);
#pragma unroll
        for (int ksl = 0; ksl < 2; ++ksl) {
            const bf16x8 bA = bfr[0][kq * 2 + ksl];
            const bf16x8 bB = bfr[1][kq * 2 + ksl];
#pragma unroll
            for (int ntl = 0; ntl < 8; ++ntl) {
                const bf16x8 wfr = frag_at(slot, ksl * 8 + ntl);
                A[0][ntl] = MF(wfr, bA, A[0][ntl]);
                A[1][ntl] = MF(wfr, bB, A[1][ntl]);
            }
        }
        __builtin_amdgcn_s_setprio(0);
    };

    const float* sb1 = sb;        // scaled biases, layer 1..3
    const float* sb2 = sb + 256;
    const float* sb3 = sb + 512;

    init_half(accA, sb, 0);       // wait: L0 uses b0 scaled = sb? no — sb is b1..?  (see host: sb[0]=b0)
    // NOTE: host writes sb[0..3] = scaled b0,b1,b2,b3. So:
    // sb+0 = b0s, sb+256 = b1s, sb+512 = b2s, sb+768 = b3s.
    init_half(accB, sb, 8);
    __syncthreads();                    // chunks 0,1 staged

    // ---- interval 0: L0 (chunk 0) ----
    __builtin_amdgcn_s_setprio(1);
#pragma unroll
    for (int ntl = 0; ntl < 8; ++ntl) {
        const bf16x8 wl = frag_at(0, ntl);
        const bf16x8 wh = frag_at(0, 8 + ntl);
        accA[0][ntl] = MF(wl, af0[0], accA[0][ntl]);
        accA[1][ntl] = MF(wl, af0[1], accA[1][ntl]);
        accB[0][ntl] = MF(wh, af0[0], accB[0][ntl]);
        accB[1][ntl] = MF(wh, af0[1], accB[1][ntl]);
    }
    __builtin_amdgcn_s_setprio(0);
    __syncthreads(); stage(2);

    // one-time serial: pack A of L0, re-init accA for layer 1
    pack_half(accA, 0);
    init_half(accA, sb + 256, 0);

    // ---- steady layer: chunks ib..ib+7 = A0 A1 A2 A3 B0 B1 B2 B3 ----
    // sbL = this layer's scaled bias (for accB init); sbN = next layer's (for accA), may be null
    auto layer = [&](int ib, const float* sbL, const float* sbN) {
        // i1 (A0, kq0): pack B(prev) + init B overlap the MFMAs
        pack_half(accB, 4);
        init_half(accB, sbL, 8);
        chunk_mfma(ib & 1, 0, accA);
        __syncthreads(); stage(ib + 2);
        // i2 (A1, kq1)
        chunk_mfma((ib + 1) & 1, 1, accA);
        __syncthreads(); stage(ib + 3);
        // i3 (A2, kq2)
        chunk_mfma((ib + 2) & 1, 2, accA);
        __syncthreads(); stage(ib + 4);
        // i4 (A3, kq3) -> accA complete
        chunk_mfma((ib + 3) & 1, 3, accA);
        __syncthreads(); stage(ib + 5);
        // i5 (B0, kq0): pack A(this layer) + init A(next) overlap
        pack_half(accA, 0);
        if (sbN) init_half(accA, sbN, 0);
        chunk_mfma((ib + 4) & 1, 0, accB);
        __syncthreads(); stage(ib + 6);
        // i6..i8 (B1..B3)
        chunk_mfma((ib + 5) & 1, 1, accB);
        __syncthreads(); stage(ib + 7);
        chunk_mfma((ib + 6) & 1, 2, accB);
        __syncthreads(); stage(ib + 8);
        chunk_mfma((ib + 7) & 1, 3, accB);
        __syncthreads(); stage(ib + 9);
    };

    layer(1,  sb + 256, sb + 512);   // layer 1 (W1): accB bias b1s, next accA bias b2s
    layer(9,  sb + 512, sb + 768);   // layer 2
    layer(17, sb + 768, nullptr);    // layer 3 (accA freed for final)

    // ---- final (chunk 25 = Wf): bfr[0..3] packed at layer3-i5 ----
    {
        f32x4 fo[2] = {{0, 0, 0, 0}, {0, 0, 0, 0}};
#pragma unroll
        for (int ks = 0; ks < 4; ++ks) {          // independent of accB
            const bf16x8 wfr = frag_at(25 & 1, ks);
            fo[0] = MF(wfr, bfr[0][ks], fo[0]);
            fo[1] = MF(wfr, bfr[1][ks], fo[1]);
        }
        pack_half(accB, 4);                        // overlaps the 8 MFMAs above
#pragma unroll
        for (int ks = 4; ks < 8; ++ks) {
            const bf16x8 wfr = frag_at(25 & 1, ks);
            fo[0] = MF(wfr, bfr[0][ks], fo[0]);
            fo[1] = MF(wfr, bfr[1][ks], fo[1]);
        }
        if (g == 0) {
#pragma unroll
            for (int ptt = 0; ptt < 2; ++ptt) {
                const long long oi = base + w * 32 + ptt * 16 + p16;
                if (oi < total) {
                    float4 o;
                    o.x = fast_sigmoid(fo[ptt][0] + bfin[0]);
                    o.y = fast_sigmoid(fo[ptt][1] + bfin[1]);
                    o.z = fast_sigmoid(fo[ptt][2] + bfin[2]);
                    o.w = fo[ptt][3] + bfin[3];
                    *(float4*)(out + oi * 4) = o;
                }
            }
        }
    }
}

extern "C" void kernel_launch(void* const* d_in, const int* in_sizes, int n_in,
                              void* d_out, int out_size, void* d_ws, size_t ws_size,
                              hipStream_t stream) {
    const float* points = (const float*)d_in[0];
    const float* vol    = (const float*)d_in[1];
    const float* W0 = (const float*)d_in[2];
    const float* b0 = (const float*)d_in[3];
    const float* W1 = (const float*)d_in[4];
    const float* b1 = (const float*)d_in[5];
    const float* W2 = (const float*)d_in[6];
    const float* b2 = (const float*)d_in[7];
    const float* W3 = (const float*)d_in[8];
    const float* b3 = (const float*)d_in[9];
    const float* Wf = (const float*)d_in[10];
    const float* bf = (const float*)d_in[11];

    const int B = in_sizes[1] / (32 * 32 * 32 * 32);
    const int N = in_sizes[0] / (3 * B);
    const long long total = (long long)B * N;
    const int tiles = (int)((total + 127) / 128);

    ushort* Wstream = (ushort*)d_ws;
    float* sb = (float*)((char*)d_ws + STREAM_BYTES);   // scaled b0..b3
    build_frags<<<104, 256, 0, stream>>>(W0, W1, W2, W3, Wf, Wstream);
    scale_biases<<<4, 256, 0, stream>>>(b0, b1, b2, b3, sb);

    const size_t fixed = (size_t)STREAM_BYTES + SBIAS_BYTES;
    const int use_cl = (ws_size >= fixed + (size_t)B * 32768 * 32 * 4) ? 1 : 0;
    float* volcl = (float*)((char*)d_ws + fixed);
    if (use_cl) {
        const int nvox = B * 32768;
        vol_chlast<<<(nvox + 255) / 256, 256, 0, stream>>>(vol, volcl, nvox);
    }

    siren_pl<<<tiles, THREADS, 0, stream>>>(
        points, vol, bf, Wstream, sb, volcl, use_cl,
        (float*)d_out, total, N);
}

// Round 13
// 102.579 us; speedup vs baseline: 5.6641x; 1.0409x over previous
//
#include <hip/hip_runtime.h>
#include <math.h>

#define THREADS 256   // 4 waves/block, 32 pts/wave, 128 pts/block

typedef __attribute__((ext_vector_type(8))) short bf16x8;
typedef __attribute__((ext_vector_type(4))) float f32x4;

#define INV2PI 0.15915494309189535f

// ---------------------------------------------------------------------------
// ws layout: [stream 26x16KB][scaled biases 4x256 f32][volcl f32]
// Frag = 1KB (16 neurons x 32 k). 416 frags, 16/chunk.
//   chunk 0      : L0 (W0 256x32, x1/2pi): frags nt=0..15
//   chunks 1..24 : per layer 8 chunks, order A0 B0 A1 B1 A2 B2 A3 B3
//       (A: nt 0..7, B: nt 8..15; kq = sub>>1; x1/2pi)
//     within chunk: idx = ksl*8 + ntl  (ksl 0..1 -> halves, ntl 0..7)
//   chunk 25     : Wf frags ks=0..7 (rows>=4 zero, UNscaled) + 8 zero frags
#define NCHUNK 26
#define STREAM_BYTES (NCHUNK * 16384)
#define SBIAS_BYTES 4096

__device__ __host__ __forceinline__ int sigma_k(int k) {
    // bits [b7 b6 b5 | b4 b3 | b2 b1 | b0] -> [b7 b6 b5 | b2 | b4 b3 | b1 | b0]
    return (k & 0xE1) | ((k & 0x04) << 2) | ((k & 0x18) >> 1) | (k & 0x02);
}

__device__ __forceinline__ ushort f2bf(float f) {
    union { float f; unsigned u; } v; v.f = f;
    unsigned r = v.u + 0x7FFFu + ((v.u >> 16) & 1u);
    return (ushort)(r >> 16);
}

__device__ __forceinline__ float fast_sigmoid(float x) {
    return 1.0f / (1.0f + __expf(-x));
}

__device__ __forceinline__ unsigned cvt_pk_bf16(float lo, float hi) {
    unsigned d;
    asm("v_cvt_pk_bf16_f32 %0, %1, %2" : "=v"(d) : "v"(lo), "v"(hi));
    return d;
}

// hardware sin, input in REVOLUTIONS (weights/biases pre-scaled by 1/2pi)
__device__ __forceinline__ float hw_sin(float x) {
    float r;
    asm("v_sin_f32 %0, %1" : "=v"(r) : "v"(x));
    return r;
}

// ---------------- prep kernels ----------------
__global__ void build_frags(const float* __restrict__ W0,
                            const float* __restrict__ W1,
                            const float* __restrict__ W2,
                            const float* __restrict__ W3,
                            const float* __restrict__ Wf,
                            ushort* __restrict__ stream) {
    const int gid = blockIdx.x * 256 + threadIdx.x;   // 0 .. 26623
    const int f = gid >> 6;                            // frag 0..415
    if (f >= 416) return;
    const int lane = gid & 63;
    const int p16 = lane & 15, g = lane >> 4;
    ushort* dst = stream + (size_t)f * 512 + lane * 8;

    if (f < 16) {                       // L0: W0[f*16+p16][8g+i] * 1/2pi
        const float* row = W0 + (size_t)(f * 16 + p16) * 32;
#pragma unroll
        for (int i = 0; i < 8; ++i) dst[i] = f2bf(row[8 * g + i] * INV2PI);
    } else if (f < 400) {
        const int t = f - 16;
        const int h = t >> 7;           // layer: 0,1,2 -> W1,W2,W3
        const int r = t & 127;
        const int sub = r >> 4;         // 0..7 = A0 B0 A1 B1 A2 B2 A3 B3
        const int idx = r & 15;
        const int q = sub & 1;          // 0=A(nt0..7) 1=B(nt8..15)
        const int kq = sub >> 1;        // ks pair 0..3
        const int ksl = idx >> 3;       // 0..1 (half)
        const int ntl = idx & 7;
        const int nt = q * 8 + ntl;
        const int ks = kq * 2 + ksl;
        const float* W = (h == 0) ? W1 : (h == 1) ? W2 : W3;
        const float* row = W + (size_t)(nt * 16 + p16) * 256;
#pragma unroll
        for (int i = 0; i < 8; ++i) dst[i] = f2bf(row[sigma_k(32 * ks + 8 * g + i)] * INV2PI);
    } else if (f < 408) {               // Wf (unscaled)
        const int ks = f - 400;
        if (p16 < 4) {
            const float* row = Wf + (size_t)p16 * 256;
#pragma unroll
            for (int i = 0; i < 8; ++i) dst[i] = f2bf(row[sigma_k(32 * ks + 8 * g + i)]);
        } else {
#pragma unroll
            for (int i = 0; i < 8; ++i) dst[i] = 0;
        }
    } else {
#pragma unroll
        for (int i = 0; i < 8; ++i) dst[i] = 0;
    }
}

__global__ void scale_biases(const float* __restrict__ b0, const float* __restrict__ b1,
                             const float* __restrict__ b2, const float* __restrict__ b3,
                             float* __restrict__ sb) {
    const int i = blockIdx.x * 256 + threadIdx.x;   // 0..1023
    const int l = i >> 8, j = i & 255;
    const float* b = (l == 0) ? b0 : (l == 1) ? b1 : (l == 2) ? b2 : b3;
    sb[i] = b[j] * INV2PI;
}

// vol [B][32][32768] f32 -> dst [B*32768][32] f32 (channel-last)
__global__ void vol_chlast(const float* __restrict__ vol, float* __restrict__ dst, int nvox) {
    int v = blockIdx.x * 256 + threadIdx.x;
    if (v >= nvox) return;
    const int b = v >> 15, idx = v & 32767;
    const float* s = vol + (size_t)b * 32 * 32768 + idx;
    float* d = dst + (size_t)v * 32;
#pragma unroll
    for (int c = 0; c < 32; ++c) d[c] = s[(size_t)c * 32768];
}

// ---------------- main fused kernel ----------------
#define MF(a, b, c) __builtin_amdgcn_mfma_f32_16x16x32_bf16((a), (b), (c), 0, 0, 0)

__global__ __launch_bounds__(THREADS, 2)
void siren_pl(const float* __restrict__ points,
              const float* __restrict__ vol,
              const float* __restrict__ bfin,
              const ushort* __restrict__ Wstream,
              const float* __restrict__ sb,       // scaled biases [4][256]
              const float* __restrict__ volcl, int use_cl,
              float* __restrict__ out, long long total, int N) {
    __shared__ ushort ring[3 * 8192];   // 3 x 16KB -> 48KB/block, 2 blocks/CU

    const int tid = (int)threadIdx.x;
    const int w = tid >> 6;             // wave 0..3
    const int lane = tid & 63;
    const int p16 = lane & 15;
    const int g = lane >> 4;

    const long long base = (long long)blockIdx.x * 128;

    auto stage = [&](int c) {
        if (c >= NCHUNK) return;
        const ushort* src = Wstream + (size_t)c * 8192;
        ushort* dstbase = ring + (c % 3) * 8192;
#pragma unroll
        for (int q = 0; q < 4; ++q) {
            const int off = (q * 4 + w) * 512;   // elements; wave-uniform
            __builtin_amdgcn_global_load_lds(
                (const __attribute__((address_space(1))) unsigned int*)(src + off + lane * 8),
                (__attribute__((address_space(3))) unsigned int*)(dstbase + off),
                16, 0, 0);
        }
    };
    stage(0);
    stage(1);
    stage(2);   // 3-deep lead: chunk c+1 is always landed one barrier early

    // ---- sample 2 points per lane: channels 8g..8g+7 ----
    bf16x8 af0[2];
    {
#pragma unroll
        for (int ptt = 0; ptt < 2; ++ptt) {
            const long long gidx = base + w * 32 + ptt * 16 + p16;
            const long long gp = gidx < total ? gidx : total - 1;
            const int bi = (int)(gp / N);
            const float* pp = points + gp * 3;
            const float sc = 1.0f / 0.6f;
            const float ix = (pp[0] * sc + 1.0f) * 16.0f - 0.5f;
            const float iy = (pp[1] * sc + 1.0f) * 16.0f - 0.5f;
            const float iz = (pp[2] * sc + 1.0f) * 16.0f - 0.5f;
            const float fx = floorf(ix), fy = floorf(iy), fz = floorf(iz);
            const float wx = ix - fx, wy = iy - fy, wz = iz - fz;
            const int x0 = (int)fminf(fmaxf(fx, 0.0f), 31.0f);
            const int x1 = (int)fminf(fmaxf(fx + 1.0f, 0.0f), 31.0f);
            const int y0 = (int)fminf(fmaxf(fy, 0.0f), 31.0f);
            const int y1 = (int)fminf(fmaxf(fy + 1.0f, 0.0f), 31.0f);
            const int z0 = (int)fminf(fmaxf(fz, 0.0f), 31.0f);
            const int z1 = (int)fminf(fmaxf(fz + 1.0f, 0.0f), 31.0f);
            const int i000 = (z0 * 32 + y0) * 32 + x0, i001 = (z0 * 32 + y0) * 32 + x1;
            const int i010 = (z0 * 32 + y1) * 32 + x0, i011 = (z0 * 32 + y1) * 32 + x1;
            const int i100 = (z1 * 32 + y0) * 32 + x0, i101 = (z1 * 32 + y0) * 32 + x1;
            const int i110 = (z1 * 32 + y1) * 32 + x0, i111 = (z1 * 32 + y1) * 32 + x1;
            const float omx = 1.0f - wx, omy = 1.0f - wy, omz = 1.0f - wz;
            const float w000 = omz * omy * omx, w001 = omz * omy * wx;
            const float w010 = omz * wy * omx,  w011 = omz * wy * wx;
            const float w100 = wz * omy * omx,  w101 = wz * omy * wx;
            const float w110 = wz * wy * omx,   w111 = wz * wy * wx;

            f32x4 a[2];
            if (use_cl) {
                const float* vb = volcl + (size_t)bi * 32768 * 32 + g * 8;
#pragma unroll
                for (int h = 0; h < 2; ++h) {
                    const float* vh = vb + h * 4;
                    a[h]  = w000 * *(const f32x4*)(vh + (size_t)i000 * 32);
                    a[h] += w001 * *(const f32x4*)(vh + (size_t)i001 * 32);
                    a[h] += w010 * *(const f32x4*)(vh + (size_t)i010 * 32);
                    a[h] += w011 * *(const f32x4*)(vh + (size_t)i011 * 32);
                    a[h] += w100 * *(const f32x4*)(vh + (size_t)i100 * 32);
                    a[h] += w101 * *(const f32x4*)(vh + (size_t)i101 * 32);
                    a[h] += w110 * *(const f32x4*)(vh + (size_t)i110 * 32);
                    a[h] += w111 * *(const f32x4*)(vh + (size_t)i111 * 32);
                }
            } else {
                const float* vb = vol + ((size_t)bi * 32 + (size_t)g * 8) * 32768;
#pragma unroll
                for (int c = 0; c < 8; ++c) {
                    const float* vc = vb + (size_t)c * 32768;
                    a[c >> 2][c & 3] =
                        vc[i000] * w000 + vc[i001] * w001 + vc[i010] * w010 + vc[i011] * w011 +
                        vc[i100] * w100 + vc[i101] * w101 + vc[i110] * w110 + vc[i111] * w111;
                }
            }
            union { bf16x8 v; unsigned u[4]; } pk;
            pk.u[0] = cvt_pk_bf16(a[0][0], a[0][1]);
            pk.u[1] = cvt_pk_bf16(a[0][2], a[0][3]);
            pk.u[2] = cvt_pk_bf16(a[1][0], a[1][1]);
            pk.u[3] = cvt_pk_bf16(a[1][2], a[1][3]);
            af0[ptt] = pk.v;
        }
    }

    f32x4 accA[2][8];   // nt 0..7
    f32x4 accB[2][8];   // nt 8..15
    bf16x8 bfr[2][8];   // activations, ks=0..7
    bf16x8 wreg[8];     // rotating weight-frag buffer (software pipeline)

    auto frag_at = [&](int slot, int idx) -> bf16x8 {
        return *(const bf16x8*)&ring[slot * 8192 + idx * 512 + lane * 8];
    };
    auto init_half = [&](f32x4 (&A)[2][8], const float* __restrict__ b, int ntbase) {
#pragma unroll
        for (int m = 0; m < 8; ++m) {
            const f32x4 bv = *(const f32x4*)&b[(ntbase + m) * 16 + 4 * g];
            A[0][m] = bv; A[1][m] = bv;
        }
    };
    auto pack_half = [&](f32x4 (&A)[2][8], int ksbase) {
#pragma unroll
        for (int ptt = 0; ptt < 2; ++ptt)
#pragma unroll
            for (int ks2 = 0; ks2 < 4; ++ks2) {
                union { bf16x8 v; unsigned u[4]; } pk;
#pragma unroll
                for (int j = 0; j < 4; ++j) {
                    const int m = 2 * ks2 + (j >> 1);
                    const int r = 2 * (j & 1);
                    pk.u[j] = cvt_pk_bf16(hw_sin(A[ptt][m][r]), hw_sin(A[ptt][m][r + 1]));
                }
                bfr[ptt][ksbase + ks2] = pk.v;
            }
    };
    // consume one half-chunk (8 frags) from wreg; rotate-prefetch the next
    // half (nslot, nbase) into the freed registers. Reads trail ~16 MFMAs.
    auto mfma_half = [&](int kq, int ksl, f32x4 (&A)[2][8], int nslot, int nbase) {
        const bf16x8 bA = bfr[0][kq * 2 + ksl];
        const bf16x8 bB = bfr[1][kq * 2 + ksl];
        __builtin_amdgcn_s_setprio(1);
#pragma unroll
        for (int ntl = 0; ntl < 8; ++ntl) {
            A[0][ntl] = MF(wreg[ntl], bA, A[0][ntl]);
            A[1][ntl] = MF(wreg[ntl], bB, A[1][ntl]);
            wreg[ntl] = frag_at(nslot, nbase + ntl);
        }
        __builtin_amdgcn_s_setprio(0);
    };

    init_half(accA, sb, 0);             // sb+0 = scaled b0
    init_half(accB, sb, 8);
    __syncthreads();                    // chunks 0,1,2 staged & landed

    // preload chunk0 half0
#pragma unroll
    for (int i = 0; i < 8; ++i) wreg[i] = frag_at(0, i);

    // ---- interval 0: L0 (chunk 0: half0 -> accA, half1 -> accB) ----
    __builtin_amdgcn_s_setprio(1);
#pragma unroll
    for (int ntl = 0; ntl < 8; ++ntl) {
        accA[0][ntl] = MF(wreg[ntl], af0[0], accA[0][ntl]);
        accA[1][ntl] = MF(wreg[ntl], af0[1], accA[1][ntl]);
        wreg[ntl] = frag_at(0, 8 + ntl);          // chunk0 half1
    }
#pragma unroll
    for (int ntl = 0; ntl < 8; ++ntl) {
        accB[0][ntl] = MF(wreg[ntl], af0[0], accB[0][ntl]);
        accB[1][ntl] = MF(wreg[ntl], af0[1], accB[1][ntl]);
        wreg[ntl] = frag_at(1, ntl);              // chunk1 half0
    }
    __builtin_amdgcn_s_setprio(0);
    __syncthreads(); stage(3);

    // ---- steady layer: chunks cbase..cbase+7 = A0 B0 A1 B1 A2 B2 A3 B3 ----
    // packs of PREV layer's accs happen at entry (A) and after chunk0 (B);
    // verified dataflow: bfr[0..3]=prev-A, bfr[4..7]=prev-B, all consumed
    // before overwrite at next layer entry.
#define LCH(k, ACC, KQ)                                                \
        mfma_half(KQ, 0, ACC, ((cbase) + (k)) % 3, 8);                 \
        mfma_half(KQ, 1, ACC, ((cbase) + (k) + 1) % 3, 0);             \
        __syncthreads(); stage((cbase) + (k) + 3);

#define LAYER(CB, SBL)                                                 \
    do {                                                               \
        const int cbase = (CB);                                        \
        pack_half(accA, 0); init_half(accA, (SBL), 0);                 \
        LCH(0, accA, 0)                                                \
        pack_half(accB, 4); init_half(accB, (SBL), 8);                 \
        LCH(1, accB, 0)                                                \
        LCH(2, accA, 1)                                                \
        LCH(3, accB, 1)                                                \
        LCH(4, accA, 2)                                                \
        LCH(5, accB, 2)                                                \
        LCH(6, accA, 3)                                                \
        LCH(7, accB, 3)                                                \
    } while (0)

    LAYER(1,  sb + 256);   // W1
    LAYER(9,  sb + 512);   // W2
    LAYER(17, sb + 768);   // W3
    // last LCH preloaded chunk 25 half0 (= Wf frags ks 0..7) into wreg

    // ---- final: Wf from wreg ----
    pack_half(accA, 0);
    pack_half(accB, 4);
    {
        f32x4 fo[2] = {{0, 0, 0, 0}, {0, 0, 0, 0}};
#pragma unroll
        for (int ks = 0; ks < 8; ++ks) {
            fo[0] = MF(wreg[ks], bfr[0][ks], fo[0]);
            fo[1] = MF(wreg[ks], bfr[1][ks], fo[1]);
        }
        if (g == 0) {
#pragma unroll
            for (int ptt = 0; ptt < 2; ++ptt) {
                const long long oi = base + w * 32 + ptt * 16 + p16;
                if (oi < total) {
                    float4 o;
                    o.x = fast_sigmoid(fo[ptt][0] + bfin[0]);
                    o.y = fast_sigmoid(fo[ptt][1] + bfin[1]);
                    o.z = fast_sigmoid(fo[ptt][2] + bfin[2]);
                    o.w = fo[ptt][3] + bfin[3];
                    *(float4*)(out + oi * 4) = o;
                }
            }
        }
    }
}

extern "C" void kernel_launch(void* const* d_in, const int* in_sizes, int n_in,
                              void* d_out, int out_size, void* d_ws, size_t ws_size,
                              hipStream_t stream) {
    const float* points = (const float*)d_in[0];
    const float* vol    = (const float*)d_in[1];
    const float* W0 = (const float*)d_in[2];
    const float* b0 = (const float*)d_in[3];
    const float* W1 = (const float*)d_in[4];
    const float* b1 = (const float*)d_in[5];
    const float* W2 = (const float*)d_in[6];
    const float* b2 = (const float*)d_in[7];
    const float* W3 = (const float*)d_in[8];
    const float* b3 = (const float*)d_in[9];
    const float* Wf = (const float*)d_in[10];
    const float* bf = (const float*)d_in[11];

    const int B = in_sizes[1] / (32 * 32 * 32 * 32);
    const int N = in_sizes[0] / (3 * B);
    const long long total = (long long)B * N;
    const int tiles = (int)((total + 127) / 128);

    ushort* Wstream = (ushort*)d_ws;
    float* sb = (float*)((char*)d_ws + STREAM_BYTES);   // scaled b0..b3
    build_frags<<<104, 256, 0, stream>>>(W0, W1, W2, W3, Wf, Wstream);
    scale_biases<<<4, 256, 0, stream>>>(b0, b1, b2, b3, sb);

    const size_t fixed = (size_t)STREAM_BYTES + SBIAS_BYTES;
    const int use_cl = (ws_size >= fixed + (size_t)B * 32768 * 32 * 4) ? 1 : 0;
    float* volcl = (float*)((char*)d_ws + fixed);
    if (use_cl) {
        const int nvox = B * 32768;
        vol_chlast<<<(nvox + 255) / 256, 256, 0, stream>>>(vol, volcl, nvox);
    }

    siren_pl<<<tiles, THREADS, 0, stream>>>(
        points, vol, bf, Wstream, sb, volcl, use_cl,
        (float*)d_out, total, N);
}